// Round 13
// baseline (289.148 us; speedup 1.0000x reference)
//
#include <hip/hip_runtime.h>
#include <hip/hip_fp16.h>

// Monotone rational-quadratic spline transform (neural spline flow bin eval).
// inputs [64,4096,128] f32; widths [128,8]; heights [128,8]; derivs [128,9].
// R10 post-mortem: conflicts fixed (2.5e6, ~5%), f16-compressed params OK,
// but dur stuck at 87us with VALU 38% / LDS ~15% / HBM 29% -- latency-bound,
// MLP=1 (one load in flight per wave; stall ~700cy per 350cy of compute).
// R11: batch-4 independent global loads per outer iter, pinned via volatile
// asm -> all 4 loads issue before any compute. MLP x4.
// R11 compile fix: "+v" on float4 is a tied indirect register input (LLVM
// unsupported) -- pin the 16 SCALAR components instead (scalars worked in R10).

constexpr float TAILF  = 3.0f;
constexpr float EPSF   = 1e-6f;
constexpr int   NB     = 8;
constexpr int   CH     = 128;
constexpr float MIN_BW = 0.01f;
constexpr float MIN_BH = 0.01f;
constexpr float MIN_D  = 0.01f;

__device__ __forceinline__ unsigned pack_h2(float a, float b) {
    unsigned lo = __half_as_ushort(__float2half(a));
    unsigned hi = __half_as_ushort(__float2half(b));
    return (hi << 16) | lo;
}

__global__ __launch_bounds__(512, 8) void rqs_kernel(
    const float* __restrict__ in,
    const float* __restrict__ widths,
    const float* __restrict__ heights,
    const float* __restrict__ derivs,
    float* __restrict__ out, int n4)
{
    // Param record layout: idx(c,b) = ((c>>5)*32 + (c&3)*8 + b)*8 + ((c>>2)&7).
    // idx%8 == (c>>2)&7 == lane&7 for owning lanes -> wave-wide ds_read_b128
    // spreads 8 lanes/bank-group for ANY data-dependent bin b. 16 KB.
    __shared__ float4 Par[1024];   // {cwl f32, chl f32, h2(ib,bh), h2(dl,ds)}
    // Edge cache: word addr = l*33 + j*8 + k -> bank (l+8j+k)%32,
    // distinct per lane: zero conflicts even if reads are sunk into the loop.
    __shared__ float E2[33 * 32 + 8];

    const int tid = threadIdx.x;

    // ---- per-block parameter setup: one thread per channel ----
    if (tid < CH) {
        const int c = tid;
        float cwe[NB + 1], che[NB + 1], dv[NB + 1];

        { // widths -> softmax -> affine -> cumsum -> edges in [-3,3]
            float v[NB];
            float m = -3.4e38f;
            for (int k = 0; k < NB; ++k) { v[k] = widths[c * NB + k]; m = fmaxf(m, v[k]); }
            float s = 0.f;
            for (int k = 0; k < NB; ++k) { v[k] = expf(v[k] - m); s += v[k]; }
            float cum = 0.f;
            cwe[0] = 0.f;
            for (int k = 0; k < NB; ++k) {
                float w = (v[k] / s) * (1.0f - MIN_BW * (float)NB) + MIN_BW;
                cum += w;
                cwe[k + 1] = cum;
            }
            float last = fmaxf(cwe[NB], EPSF);
            for (int k = 0; k <= NB; ++k)
                cwe[k] = 2.0f * TAILF * (cwe[k] / last) - TAILF;
        }
        { // heights -> same pipeline
            float v[NB];
            float m = -3.4e38f;
            for (int k = 0; k < NB; ++k) { v[k] = heights[c * NB + k]; m = fmaxf(m, v[k]); }
            float s = 0.f;
            for (int k = 0; k < NB; ++k) { v[k] = expf(v[k] - m); s += v[k]; }
            float cum = 0.f;
            che[0] = 0.f;
            for (int k = 0; k < NB; ++k) {
                float h = (v[k] / s) * (1.0f - MIN_BH * (float)NB) + MIN_BH;
                cum += h;
                che[k + 1] = cum;
            }
            float last = fmaxf(che[NB], EPSF);
            for (int k = 0; k <= NB; ++k)
                che[k] = 2.0f * TAILF * (che[k] / last) - TAILF;
        }
        // derivatives -> stable softplus + MIN_D (matches jax.nn.softplus)
        for (int k = 0; k <= NB; ++k) {
            float x = derivs[c * (NB + 1) + k];
            dv[k] = fmaxf(x, 0.f) + log1pf(expf(-fabsf(x))) + MIN_D;
        }

        const int grp = (c >> 2) & 7;
        const int mb  = ((c >> 5) & 3) * 32 + (c & 3) * 8;
        for (int b = 0; b < NB; ++b) {
            float cwl = cwe[b], cwr = cwe[b + 1];
            float chl = che[b], chr = che[b + 1];
            float bw = cwr - cwl, bh = chr - chl;
            float inv_bw = 1.0f / bw;
            float delta  = bh * inv_bw;
            float dl = dv[b], dr = dv[b + 1];
            float dsum = dl + dr - 2.0f * delta;
            int idx = (mb + b) * 8 + grp;
            Par[idx] = make_float4(cwl, chl,
                                   __uint_as_float(pack_h2(inv_bw, bh)),
                                   __uint_as_float(pack_h2(dl, dsum)));
        }
        for (int k = 0; k < 7; ++k)
            E2[(c >> 2) * 33 + (c & 3) * 8 + k] = cwe[k + 1];
    }
    __syncthreads();

    // Each thread owns 4 fixed channels c0..c0+3 (all strides are multiples
    // of 32 float4s). Edge loads pinned so they stay in the preamble.
    const int l = tid & 31;
    float e[4][7];
    #pragma unroll
    for (int j = 0; j < 4; ++j)
        #pragma unroll
        for (int k = 0; k < 7; ++k) {
            e[j][k] = E2[l * 33 + j * 8 + k];
            asm volatile("" : "+v"(e[j][k]));
        }

    const char* parbase = (const char*)Par + ((l >> 3) * 4096 + (l & 7) * 16);

    auto proc = [&](float4 x4) -> float4 {
        float xs[4] = {x4.x, x4.y, x4.z, x4.w};
        float r[4];
        #pragma unroll
        for (int j = 0; j < 4; ++j) {
            float xo = xs[j];
            float x  = fminf(fmaxf(xo, -TAILF + EPSF), TAILF - EPSF);
            int b = 0;
            #pragma unroll
            for (int k = 0; k < 7; ++k) b += (x >= e[j][k]) ? 1 : 0;
            const float4 rec = *reinterpret_cast<const float4*>(
                parbase + (b << 7) + j * 1024);        // one ds_read_b128
            float cwl = rec.x, chl = rec.y;
            unsigned uz = __float_as_uint(rec.z);
            unsigned uw = __float_as_uint(rec.w);
            float inv_bw = __half2float(__ushort_as_half((unsigned short)(uz & 0xffffu)));
            float bh     = __half2float(__ushort_as_half((unsigned short)(uz >> 16)));
            float dl     = __half2float(__ushort_as_half((unsigned short)(uw & 0xffffu)));
            float dsum   = __half2float(__ushort_as_half((unsigned short)(uw >> 16)));
            float delta  = bh * inv_bw;
            float theta  = fminf(fmaxf((x - cwl) * inv_bw, 0.f), 1.f); // v_med3
            float t1m = theta * (1.f - theta);
            float num = bh * (delta * theta * theta + dl * t1m);
            float den = delta + dsum * t1m;            // >= ~0.007 always
            float res = chl + num * __builtin_amdgcn_rcpf(den);
            bool outside = fabsf(xo) > TAILF;
            r[j] = outside ? xo : res;
        }
        return make_float4(r[0], r[1], r[2], r[3]);
    };

    const float4* __restrict__ in4  = reinterpret_cast<const float4*>(in);
    float4*       __restrict__ out4 = reinterpret_cast<float4*>(out);
    const int gtid   = blockIdx.x * blockDim.x + tid;
    const int stride = gridDim.x * blockDim.x;

    int i = gtid;
    // Batched phase: 4 independent loads in flight before any compute.
    for (; i + 3 * stride < n4; i += 4 * stride) {
        float4 x0 = in4[i];
        float4 x1 = in4[i + stride];
        float4 x2 = in4[i + 2 * stride];
        float4 x3 = in4[i + 3 * stride];
        // One volatile asm consuming all 16 loaded SCALARS ("+v" on scalars
        // only -- tied vector operands are unsupported). Every load and its
        // waitcnt must complete before anything after this point; the
        // scheduler cannot interleave load->use->load->use.
        asm volatile(""
            : "+v"(x0.x), "+v"(x0.y), "+v"(x0.z), "+v"(x0.w),
              "+v"(x1.x), "+v"(x1.y), "+v"(x1.z), "+v"(x1.w),
              "+v"(x2.x), "+v"(x2.y), "+v"(x2.z), "+v"(x2.w),
              "+v"(x3.x), "+v"(x3.y), "+v"(x3.z), "+v"(x3.w));
        out4[i]              = proc(x0);
        out4[i + stride]     = proc(x1);
        out4[i + 2 * stride] = proc(x2);
        out4[i + 3 * stride] = proc(x3);
    }
    // Generic tail (not reached at the launch config below: 16 = 4x4 exact).
    for (; i < n4; i += stride)
        out4[i] = proc(in4[i]);
}

extern "C" void kernel_launch(void* const* d_in, const int* in_sizes, int n_in,
                              void* d_out, int out_size, void* d_ws, size_t ws_size,
                              hipStream_t stream) {
    const float* in      = (const float*)d_in[0];
    const float* widths  = (const float*)d_in[1];
    const float* heights = (const float*)d_in[2];
    const float* derivs  = (const float*)d_in[3];
    float* out = (float*)d_out;

    int n4 = out_size / 4; // 33,554,432 / 4 = 8,388,608 = 16 * 524288
    // 1024 blocks x 512 thr: LDS ~20.6KB -> 4 blocks/CU (32 waves/CU),
    // 4 batch-iterations of 4 float4s per thread, no tail.
    // All strides multiples of 32 -> fixed channel ownership per lane.
    dim3 grid(1024), block(512);
    hipLaunchKernelGGL(rqs_kernel, grid, block, 0, stream,
                       in, widths, heights, derivs, out, n4);
}